// Round 1
// baseline (4623.020 us; speedup 1.0000x reference)
//
#include <hip/hip_runtime.h>

#define CDIM 128

// ---------------- softmax over P=3 of d[3][128] -> dw[3][128] ----------------
__global__ void softmax_dw_kernel(const float* __restrict__ d, float* __restrict__ dw) {
    int c = threadIdx.x;
    float d0 = d[0 * CDIM + c], d1 = d[1 * CDIM + c], d2 = d[2 * CDIM + c];
    float m = fmaxf(d0, fmaxf(d1, d2));
    float e0 = expf(d0 - m), e1 = expf(d1 - m), e2 = expf(d2 - m);
    float inv = 1.0f / (e0 + e1 + e2);
    dw[0 * CDIM + c] = e0 * inv;
    dw[1 * CDIM + c] = e1 * inv;
    dw[2 * CDIM + c] = e2 * inv;
}

// ---------------- out[n][c] = hop_bias[c] ----------------
__global__ void init_out_kernel(float* __restrict__ out, const float* __restrict__ hop_bias, int total) {
    int i = blockIdx.x * blockDim.x + threadIdx.x;
    if (i < total) out[i] = hop_bias[i & (CDIM - 1)];
}

// ---------------- degree count: deg[col] += 1 ----------------
__global__ void deg_kernel(const int* __restrict__ ei, float* __restrict__ deg, int E) {
    int e = blockIdx.x * blockDim.x + threadIdx.x;
    if (e < E) atomicAdd(&deg[ei[E + e]], 1.0f);
}

// ---------------- dinv = deg > 0 ? deg^-0.5 : 0 ----------------
__global__ void dinv_kernel(const float* __restrict__ deg, float* __restrict__ dinv, int total) {
    int i = blockIdx.x * blockDim.x + threadIdx.x;
    if (i < total) {
        float dg = deg[i];
        dinv[i] = dg > 0.0f ? (1.0f / sqrtf(dg)) : 0.0f;
    }
}

// ---------------- fp32 GEMM: y[r][c] = sum_k x[r][k]*W[c][k] + bias[c] ----------------
// MODE 0: y = acc + bias (store)
// MODE 1: y[r][c] += scale[c] * (acc + bias[c])   (non-atomic RMW; block owns rows)
// BM=128 rows/block, full C=128 cols, K=128 in 2 halves of 64. 256 threads, 8x8 micro-tile.
template <int MODE>
__global__ __launch_bounds__(256) void gemm128_kernel(
    const float* __restrict__ x, const float* __restrict__ W,
    const float* __restrict__ bias, const float* __restrict__ scale,
    float* __restrict__ y, int n) {
    __shared__ float xsT[64][CDIM];  // [k][r]
    __shared__ float ws[64][CDIM];   // [k][c]
    const int tid = threadIdx.x;
    const int row0 = blockIdx.x * 128;
    const int tr = tid >> 4;   // 0..15
    const int tc = tid & 15;   // 0..15
    const int sr = tid & 127;  // staging row/col
    const int sk = tid >> 7;   // 0..1

    float acc[8][8];
#pragma unroll
    for (int i = 0; i < 8; i++)
#pragma unroll
        for (int j = 0; j < 8; j++) acc[i][j] = 0.0f;

    for (int kh = 0; kh < 2; ++kh) {
        const int kbase = kh * 64;
        __syncthreads();
// stage x half-tile transposed: xsT[k][r]
#pragma unroll
        for (int it = 0; it < 8; ++it) {
            int k4 = it * 2 + sk;  // 0..15
            float4 xv = make_float4(0.f, 0.f, 0.f, 0.f);
            if (row0 + sr < n)
                xv = *reinterpret_cast<const float4*>(x + (size_t)(row0 + sr) * CDIM + kbase + k4 * 4);
            xsT[k4 * 4 + 0][sr] = xv.x;
            xsT[k4 * 4 + 1][sr] = xv.y;
            xsT[k4 * 4 + 2][sr] = xv.z;
            xsT[k4 * 4 + 3][sr] = xv.w;
        }
// stage W half-tile transposed: ws[k][c] = W[c][k]
#pragma unroll
        for (int it = 0; it < 8; ++it) {
            int k4 = it * 2 + sk;
            float4 wv = *reinterpret_cast<const float4*>(W + (size_t)sr * CDIM + kbase + k4 * 4);
            ws[k4 * 4 + 0][sr] = wv.x;
            ws[k4 * 4 + 1][sr] = wv.y;
            ws[k4 * 4 + 2][sr] = wv.z;
            ws[k4 * 4 + 3][sr] = wv.w;
        }
        __syncthreads();
#pragma unroll 4
        for (int k = 0; k < 64; ++k) {
            float4 a0 = *reinterpret_cast<const float4*>(&xsT[k][tr * 8]);
            float4 a1 = *reinterpret_cast<const float4*>(&xsT[k][tr * 8 + 4]);
            float4 b0 = *reinterpret_cast<const float4*>(&ws[k][tc * 8]);
            float4 b1 = *reinterpret_cast<const float4*>(&ws[k][tc * 8 + 4]);
            float a[8] = {a0.x, a0.y, a0.z, a0.w, a1.x, a1.y, a1.z, a1.w};
            float b[8] = {b0.x, b0.y, b0.z, b0.w, b1.x, b1.y, b1.z, b1.w};
#pragma unroll
            for (int i = 0; i < 8; i++)
#pragma unroll
                for (int j = 0; j < 8; j++) acc[i][j] = fmaf(a[i], b[j], acc[i][j]);
        }
    }

    float bb[8];
#pragma unroll
    for (int j = 0; j < 8; j++) bb[j] = bias[tc * 8 + j];

    if (MODE == 0) {
#pragma unroll
        for (int i = 0; i < 8; i++) {
            int row = row0 + tr * 8 + i;
            if (row < n) {
                float4 o0 = make_float4(acc[i][0] + bb[0], acc[i][1] + bb[1],
                                        acc[i][2] + bb[2], acc[i][3] + bb[3]);
                float4 o1 = make_float4(acc[i][4] + bb[4], acc[i][5] + bb[5],
                                        acc[i][6] + bb[6], acc[i][7] + bb[7]);
                *reinterpret_cast<float4*>(y + (size_t)row * CDIM + tc * 8) = o0;
                *reinterpret_cast<float4*>(y + (size_t)row * CDIM + tc * 8 + 4) = o1;
            }
        }
    } else {
        float sc[8];
#pragma unroll
        for (int j = 0; j < 8; j++) sc[j] = scale[tc * 8 + j];
#pragma unroll
        for (int i = 0; i < 8; i++) {
            int row = row0 + tr * 8 + i;
            if (row < n) {
                float4* p0 = reinterpret_cast<float4*>(y + (size_t)row * CDIM + tc * 8);
                float4* p1 = reinterpret_cast<float4*>(y + (size_t)row * CDIM + tc * 8 + 4);
                float4 o0 = *p0, o1 = *p1;
                o0.x += sc[0] * (acc[i][0] + bb[0]);
                o0.y += sc[1] * (acc[i][1] + bb[1]);
                o0.z += sc[2] * (acc[i][2] + bb[2]);
                o0.w += sc[3] * (acc[i][3] + bb[3]);
                o1.x += sc[4] * (acc[i][4] + bb[4]);
                o1.y += sc[5] * (acc[i][5] + bb[5]);
                o1.z += sc[6] * (acc[i][6] + bb[6]);
                o1.w += sc[7] * (acc[i][7] + bb[7]);
                *p0 = o0;
                *p1 = o1;
            }
        }
    }
}

// ---------------- edge kernel: out[col] += dw[c]*norm*sigmoid(k[col]+q[row])*v[row] ----------------
__global__ __launch_bounds__(256) void edge_kernel(
    const int* __restrict__ ei, const float* __restrict__ ew,
    const float* __restrict__ kbuf, const float* __restrict__ qbuf,
    const float* __restrict__ vbuf, const float* __restrict__ dinv,
    const float* __restrict__ dwp, float* __restrict__ out, int E) {
    int e = blockIdx.x * 8 + (threadIdx.x >> 5);
    if (e >= E) return;
    int lane = threadIdx.x & 31;
    int row = ei[e];       // source j
    int col = ei[E + e];   // target i
    float norm = dinv[row] * dinv[col] * ew[e];
    float4 kk = reinterpret_cast<const float4*>(kbuf + (size_t)col * CDIM)[lane];
    float4 qq = reinterpret_cast<const float4*>(qbuf + (size_t)row * CDIM)[lane];
    float4 vv = reinterpret_cast<const float4*>(vbuf + (size_t)row * CDIM)[lane];
    float4 dd = reinterpret_cast<const float4*>(dwp)[lane];
    float4 m;
    m.x = norm * dd.x * vv.x / (1.0f + expf(-(kk.x + qq.x)));
    m.y = norm * dd.y * vv.y / (1.0f + expf(-(kk.y + qq.y)));
    m.z = norm * dd.z * vv.z / (1.0f + expf(-(kk.z + qq.z)));
    m.w = norm * dd.w * vv.w / (1.0f + expf(-(kk.w + qq.w)));
    float* op = out + (size_t)col * CDIM + lane * 4;
    atomicAdd(op + 0, m.x);
    atomicAdd(op + 1, m.y);
    atomicAdd(op + 2, m.z);
    atomicAdd(op + 3, m.w);
}

extern "C" void kernel_launch(void* const* d_in, const int* in_sizes, int n_in,
                              void* d_out, int out_size, void* d_ws, size_t ws_size,
                              hipStream_t stream) {
    const float* x = (const float*)d_in[0];
    const int* ei[3] = {(const int*)d_in[1], (const int*)d_in[2], (const int*)d_in[3]};
    const float* ew[3] = {(const float*)d_in[4], (const float*)d_in[5], (const float*)d_in[6]};
    const float* Wk = (const float*)d_in[7];
    const float* bk = (const float*)d_in[8];
    const float* Wq = (const float*)d_in[9];
    const float* bq = (const float*)d_in[10];
    const float* Wv = (const float*)d_in[11];
    const float* bv = (const float*)d_in[12];
    const float* Wskip = (const float*)d_in[13];
    const float* cbias = (const float*)d_in[14];
    const float* d = (const float*)d_in[15];
    const float* hop_bias = (const float*)d_in[16];
    float* out = (float*)d_out;

    const int N = in_sizes[0] / CDIM;   // 50000
    const int E = in_sizes[4];          // 800000

    // workspace layout (floats)
    float* wsf = (float*)d_ws;
    float* dw = wsf;                    // 3*128
    float* deg = dw + 3 * CDIM;         // 3*N
    float* dinv = deg + 3 * N;          // 3*N
    float* kbuf = dinv + 3 * N;         // N*C
    float* qbuf = kbuf + (size_t)N * CDIM;
    float* vbuf = qbuf + (size_t)N * CDIM;

    hipMemsetAsync(deg, 0, (size_t)3 * N * sizeof(float), stream);
    softmax_dw_kernel<<<1, CDIM, 0, stream>>>(d, dw);
    init_out_kernel<<<(N * CDIM + 255) / 256, 256, 0, stream>>>(out, hop_bias, N * CDIM);
    for (int p = 0; p < 3; ++p)
        deg_kernel<<<(E + 255) / 256, 256, 0, stream>>>(ei[p], deg + (size_t)p * N, E);
    dinv_kernel<<<(3 * N + 255) / 256, 256, 0, stream>>>(deg, dinv, 3 * N);

    const int gemm_blocks = (N + 127) / 128;
    for (int p = 0; p < 3; ++p) {
        const float* Wkp = Wk + (size_t)p * CDIM * CDIM;
        const float* Wqp = Wq + (size_t)p * CDIM * CDIM;
        const float* Wvp = Wv + (size_t)p * CDIM * CDIM;
        const float* Wsp = Wskip + (size_t)p * CDIM * CDIM;
        const float* bkp = bk + (size_t)p * CDIM;
        const float* bqp = bq + (size_t)p * CDIM;
        const float* bvp = bv + (size_t)p * CDIM;
        const float* cbp = cbias + (size_t)p * CDIM;
        const float* dwp = dw + (size_t)p * CDIM;

        gemm128_kernel<0><<<gemm_blocks, 256, 0, stream>>>(x, Wkp, bkp, nullptr, kbuf, N);
        gemm128_kernel<0><<<gemm_blocks, 256, 0, stream>>>(x, Wqp, bqp, nullptr, qbuf, N);
        gemm128_kernel<0><<<gemm_blocks, 256, 0, stream>>>(x, Wvp, bvp, nullptr, vbuf, N);
        gemm128_kernel<1><<<gemm_blocks, 256, 0, stream>>>(x, Wsp, cbp, dwp, out, N);
        edge_kernel<<<(E + 7) / 8, 256, 0, stream>>>(ei[p], ew[p], kbuf, qbuf, vbuf,
                                                     dinv + (size_t)p * N, dwp, out, E);
    }
}

// Round 2
// 1099.037 us; speedup vs baseline: 4.2064x; 4.2064x over previous
//
#include <hip/hip_runtime.h>

#define CDIM 128
#define SCAN_BLK 512

// ---------------- softmax over P=3 of d[3][128] -> dw[3][128] ----------------
__global__ void softmax_dw_kernel(const float* __restrict__ d, float* __restrict__ dw) {
    int c = threadIdx.x;
    float d0 = d[0 * CDIM + c], d1 = d[1 * CDIM + c], d2 = d[2 * CDIM + c];
    float m = fmaxf(d0, fmaxf(d1, d2));
    float e0 = expf(d0 - m), e1 = expf(d1 - m), e2 = expf(d2 - m);
    float inv = 1.0f / (e0 + e1 + e2);
    dw[0 * CDIM + c] = e0 * inv;
    dw[1 * CDIM + c] = e1 * inv;
    dw[2 * CDIM + c] = e2 * inv;
}

// ---------------- out[n][c] = hop_bias[c] ----------------
__global__ void init_out_kernel(float* __restrict__ out, const float* __restrict__ hop_bias, int total) {
    int i = blockIdx.x * blockDim.x + threadIdx.x;
    if (i < total) out[i] = hop_bias[i & (CDIM - 1)];
}

// ---------------- degree count (int): deg[col] += 1 ----------------
__global__ void deg_kernel(const int* __restrict__ ei, int* __restrict__ deg, int E) {
    int e = blockIdx.x * blockDim.x + threadIdx.x;
    if (e < E) atomicAdd(&deg[ei[E + e]], 1);
}

// ---------------- dinv = deg > 0 ? deg^-0.5 : 0 ----------------
__global__ void dinv_kernel(const int* __restrict__ deg, float* __restrict__ dinv, int n) {
    int i = blockIdx.x * blockDim.x + threadIdx.x;
    if (i < n) {
        int dg = deg[i];
        dinv[i] = dg > 0 ? rsqrtf((float)dg) : 0.0f;
    }
}

// ---------------- scan A: per-block totals of deg ----------------
__global__ __launch_bounds__(SCAN_BLK) void scanA_kernel(const int* __restrict__ deg, int* __restrict__ bsum, int n) {
    __shared__ int s[SCAN_BLK];
    int t = threadIdx.x;
    int idx = blockIdx.x * SCAN_BLK + t;
    s[t] = (idx < n) ? deg[idx] : 0;
    __syncthreads();
    for (int off = SCAN_BLK / 2; off > 0; off >>= 1) {
        if (t < off) s[t] += s[t + off];
        __syncthreads();
    }
    if (t == 0) bsum[blockIdx.x] = s[0];
}

// ---------------- scan B: exclusive scan of block sums (single block) ----------------
__global__ void scanB_kernel(int* __restrict__ bsum, int nb) {
    __shared__ int s[1024];
    int t = threadIdx.x;
    if (t < nb) s[t] = bsum[t];
    __syncthreads();
    if (t == 0) {
        int run = 0;
        for (int i = 0; i < nb; ++i) {
            int v = s[i];
            s[i] = run;
            run += v;
        }
    }
    __syncthreads();
    if (t < nb) bsum[t] = s[t];
}

// ---------------- scan C: exclusive element scan + block offset -> offs, cursor ----------------
__global__ __launch_bounds__(SCAN_BLK) void scanC_kernel(const int* __restrict__ deg, const int* __restrict__ bsum,
                                                         int* __restrict__ offs, int* __restrict__ cursor,
                                                         int n, int E) {
    __shared__ int s[SCAN_BLK];
    int t = threadIdx.x;
    int idx = blockIdx.x * SCAN_BLK + t;
    int v = (idx < n) ? deg[idx] : 0;
    s[t] = v;
    __syncthreads();
    // Hillis-Steele inclusive scan
    for (int off = 1; off < SCAN_BLK; off <<= 1) {
        int a = (t >= off) ? s[t - off] : 0;
        __syncthreads();
        s[t] += a;
        __syncthreads();
    }
    if (idx < n) {
        int ex = s[t] - v + bsum[blockIdx.x];
        offs[idx] = ex;
        cursor[idx] = ex;
    }
    if (idx == n - 1) offs[n] = E;
}

// ---------------- scatter edges into CSR buckets ----------------
__global__ __launch_bounds__(256) void scatter_kernel(const int* __restrict__ ei, const float* __restrict__ ew,
                                                      const float* __restrict__ dinv, int* __restrict__ cursor,
                                                      int* __restrict__ rows_s, float* __restrict__ norms_s, int E) {
    int e = blockIdx.x * blockDim.x + threadIdx.x;
    if (e >= E) return;
    int row = ei[e];
    int col = ei[E + e];
    float nrm = dinv[row] * dinv[col] * ew[e];
    int pos = atomicAdd(&cursor[col], 1);
    rows_s[pos] = row;
    norms_s[pos] = nrm;
}

// ---------------- fp32 GEMM: y[r][c] = sum_k x[r][k]*W[c][k] + bias[c] ----------------
template <int MODE>
__global__ __launch_bounds__(256) void gemm128_kernel(
    const float* __restrict__ x, const float* __restrict__ W,
    const float* __restrict__ bias, const float* __restrict__ scale,
    float* __restrict__ y, int n) {
    __shared__ float xsT[64][CDIM];  // [k][r]
    __shared__ float ws[64][CDIM];   // [k][c]
    const int tid = threadIdx.x;
    const int row0 = blockIdx.x * 128;
    const int tr = tid >> 4;   // 0..15
    const int tc = tid & 15;   // 0..15
    const int sr = tid & 127;
    const int sk = tid >> 7;

    float acc[8][8];
#pragma unroll
    for (int i = 0; i < 8; i++)
#pragma unroll
        for (int j = 0; j < 8; j++) acc[i][j] = 0.0f;

    for (int kh = 0; kh < 2; ++kh) {
        const int kbase = kh * 64;
        __syncthreads();
#pragma unroll
        for (int it = 0; it < 8; ++it) {
            int k4 = it * 2 + sk;
            float4 xv = make_float4(0.f, 0.f, 0.f, 0.f);
            if (row0 + sr < n)
                xv = *reinterpret_cast<const float4*>(x + (size_t)(row0 + sr) * CDIM + kbase + k4 * 4);
            xsT[k4 * 4 + 0][sr] = xv.x;
            xsT[k4 * 4 + 1][sr] = xv.y;
            xsT[k4 * 4 + 2][sr] = xv.z;
            xsT[k4 * 4 + 3][sr] = xv.w;
        }
#pragma unroll
        for (int it = 0; it < 8; ++it) {
            int k4 = it * 2 + sk;
            float4 wv = *reinterpret_cast<const float4*>(W + (size_t)sr * CDIM + kbase + k4 * 4);
            ws[k4 * 4 + 0][sr] = wv.x;
            ws[k4 * 4 + 1][sr] = wv.y;
            ws[k4 * 4 + 2][sr] = wv.z;
            ws[k4 * 4 + 3][sr] = wv.w;
        }
        __syncthreads();
#pragma unroll 4
        for (int k = 0; k < 64; ++k) {
            float4 a0 = *reinterpret_cast<const float4*>(&xsT[k][tr * 8]);
            float4 a1 = *reinterpret_cast<const float4*>(&xsT[k][tr * 8 + 4]);
            float4 b0 = *reinterpret_cast<const float4*>(&ws[k][tc * 8]);
            float4 b1 = *reinterpret_cast<const float4*>(&ws[k][tc * 8 + 4]);
            float a[8] = {a0.x, a0.y, a0.z, a0.w, a1.x, a1.y, a1.z, a1.w};
            float b[8] = {b0.x, b0.y, b0.z, b0.w, b1.x, b1.y, b1.z, b1.w};
#pragma unroll
            for (int i = 0; i < 8; i++)
#pragma unroll
                for (int j = 0; j < 8; j++) acc[i][j] = fmaf(a[i], b[j], acc[i][j]);
        }
    }

    float bb[8];
#pragma unroll
    for (int j = 0; j < 8; j++) bb[j] = bias[tc * 8 + j];

    if (MODE == 0) {
#pragma unroll
        for (int i = 0; i < 8; i++) {
            int row = row0 + tr * 8 + i;
            if (row < n) {
                float4 o0 = make_float4(acc[i][0] + bb[0], acc[i][1] + bb[1],
                                        acc[i][2] + bb[2], acc[i][3] + bb[3]);
                float4 o1 = make_float4(acc[i][4] + bb[4], acc[i][5] + bb[5],
                                        acc[i][6] + bb[6], acc[i][7] + bb[7]);
                *reinterpret_cast<float4*>(y + (size_t)row * CDIM + tc * 8) = o0;
                *reinterpret_cast<float4*>(y + (size_t)row * CDIM + tc * 8 + 4) = o1;
            }
        }
    } else {
        float sc[8];
#pragma unroll
        for (int j = 0; j < 8; j++) sc[j] = scale[tc * 8 + j];
#pragma unroll
        for (int i = 0; i < 8; i++) {
            int row = row0 + tr * 8 + i;
            if (row < n) {
                float4* p0 = reinterpret_cast<float4*>(y + (size_t)row * CDIM + tc * 8);
                float4* p1 = reinterpret_cast<float4*>(y + (size_t)row * CDIM + tc * 8 + 4);
                float4 o0 = *p0, o1 = *p1;
                o0.x += sc[0] * (acc[i][0] + bb[0]);
                o0.y += sc[1] * (acc[i][1] + bb[1]);
                o0.z += sc[2] * (acc[i][2] + bb[2]);
                o0.w += sc[3] * (acc[i][3] + bb[3]);
                o1.x += sc[4] * (acc[i][4] + bb[4]);
                o1.y += sc[5] * (acc[i][5] + bb[5]);
                o1.z += sc[6] * (acc[i][6] + bb[6]);
                o1.w += sc[7] * (acc[i][7] + bb[7]);
                *p0 = o0;
                *p1 = o1;
            }
        }
    }
}

// ---------------- gather: one wave per node; lane owns 2 channels ----------------
__global__ __launch_bounds__(256) void gather_kernel(
    const int* __restrict__ rows_s, const float* __restrict__ norms_s,
    const int* __restrict__ offs,
    const float* __restrict__ kbuf, const float* __restrict__ qbuf,
    const float* __restrict__ vbuf, const float* __restrict__ dwp,
    float* __restrict__ out, int N) {
    int node = blockIdx.x * 4 + (threadIdx.x >> 6);
    if (node >= N) return;
    int lane = threadIdx.x & 63;
    int start = offs[node];
    int end = offs[node + 1];
    float2 kk = *reinterpret_cast<const float2*>(kbuf + (size_t)node * CDIM + lane * 2);
    float2 acc = make_float2(0.f, 0.f);
    for (int base = start; base < end; base += 64) {
        int nchunk = min(64, end - base);
        int myrow = 0;
        float mynrm = 0.f;
        if (base + lane < end) {
            myrow = rows_s[base + lane];
            mynrm = norms_s[base + lane];
        }
        for (int j = 0; j < nchunk; ++j) {
            int row = __shfl(myrow, j);
            float nrm = __shfl(mynrm, j);
            float2 qq = *reinterpret_cast<const float2*>(qbuf + (size_t)row * CDIM + lane * 2);
            float2 vv = *reinterpret_cast<const float2*>(vbuf + (size_t)row * CDIM + lane * 2);
            float sx = nrm / (1.0f + __expf(-(kk.x + qq.x)));
            float sy = nrm / (1.0f + __expf(-(kk.y + qq.y)));
            acc.x = fmaf(sx, vv.x, acc.x);
            acc.y = fmaf(sy, vv.y, acc.y);
        }
    }
    float2 dd = *reinterpret_cast<const float2*>(dwp + lane * 2);
    float2* op = reinterpret_cast<float2*>(out + (size_t)node * CDIM + lane * 2);
    float2 o = *op;
    o.x += acc.x * dd.x;
    o.y += acc.y * dd.y;
    *op = o;
}

extern "C" void kernel_launch(void* const* d_in, const int* in_sizes, int n_in,
                              void* d_out, int out_size, void* d_ws, size_t ws_size,
                              hipStream_t stream) {
    const float* x = (const float*)d_in[0];
    const int* ei[3] = {(const int*)d_in[1], (const int*)d_in[2], (const int*)d_in[3]};
    const float* ew[3] = {(const float*)d_in[4], (const float*)d_in[5], (const float*)d_in[6]};
    const float* Wk = (const float*)d_in[7];
    const float* bk = (const float*)d_in[8];
    const float* Wq = (const float*)d_in[9];
    const float* bq = (const float*)d_in[10];
    const float* Wv = (const float*)d_in[11];
    const float* bv = (const float*)d_in[12];
    const float* Wskip = (const float*)d_in[13];
    const float* cbias = (const float*)d_in[14];
    const float* d = (const float*)d_in[15];
    const float* hop_bias = (const float*)d_in[16];
    float* out = (float*)d_out;

    const int N = in_sizes[0] / CDIM;  // 50000
    const int E = in_sizes[4];         // 800000
    const int nb = (N + SCAN_BLK - 1) / SCAN_BLK;

    // workspace layout
    char* wsp = (char*)d_ws;
    float* dw = (float*)wsp;                 wsp += 3 * CDIM * sizeof(float);
    int* deg = (int*)wsp;                    wsp += (size_t)N * sizeof(int);
    float* dinv = (float*)wsp;               wsp += (size_t)N * sizeof(float);
    int* offs = (int*)wsp;                   wsp += (size_t)(N + 1) * sizeof(int);
    int* cursor = (int*)wsp;                 wsp += (size_t)N * sizeof(int);
    int* bsum = (int*)wsp;                   wsp += 1024 * sizeof(int);
    int* rows_s = (int*)wsp;                 wsp += (size_t)E * sizeof(int);
    float* norms_s = (float*)wsp;            wsp += (size_t)E * sizeof(float);
    float* kbuf = (float*)wsp;               wsp += (size_t)N * CDIM * sizeof(float);
    float* qbuf = (float*)wsp;               wsp += (size_t)N * CDIM * sizeof(float);
    float* vbuf = (float*)wsp;               wsp += (size_t)N * CDIM * sizeof(float);

    softmax_dw_kernel<<<1, CDIM, 0, stream>>>(d, dw);
    init_out_kernel<<<(N * CDIM + 255) / 256, 256, 0, stream>>>(out, hop_bias, N * CDIM);

    const int gemm_blocks = (N + 127) / 128;
    for (int p = 0; p < 3; ++p) {
        const float* Wkp = Wk + (size_t)p * CDIM * CDIM;
        const float* Wqp = Wq + (size_t)p * CDIM * CDIM;
        const float* Wvp = Wv + (size_t)p * CDIM * CDIM;
        const float* Wsp = Wskip + (size_t)p * CDIM * CDIM;
        const float* bkp = bk + (size_t)p * CDIM;
        const float* bqp = bq + (size_t)p * CDIM;
        const float* bvp = bv + (size_t)p * CDIM;
        const float* cbp = cbias + (size_t)p * CDIM;
        const float* dwp = dw + (size_t)p * CDIM;

        // CSR build for hop p
        hipMemsetAsync(deg, 0, (size_t)N * sizeof(int), stream);
        deg_kernel<<<(E + 255) / 256, 256, 0, stream>>>(ei[p], deg, E);
        dinv_kernel<<<(N + 255) / 256, 256, 0, stream>>>(deg, dinv, N);
        scanA_kernel<<<nb, SCAN_BLK, 0, stream>>>(deg, bsum, N);
        scanB_kernel<<<1, 1024, 0, stream>>>(bsum, nb);
        scanC_kernel<<<nb, SCAN_BLK, 0, stream>>>(deg, bsum, offs, cursor, N, E);
        scatter_kernel<<<(E + 255) / 256, 256, 0, stream>>>(ei[p], ew[p], dinv, cursor, rows_s, norms_s, E);

        // dense projections
        gemm128_kernel<0><<<gemm_blocks, 256, 0, stream>>>(x, Wkp, bkp, nullptr, kbuf, N);
        gemm128_kernel<0><<<gemm_blocks, 256, 0, stream>>>(x, Wqp, bqp, nullptr, qbuf, N);
        gemm128_kernel<0><<<gemm_blocks, 256, 0, stream>>>(x, Wvp, bvp, nullptr, vbuf, N);
        gemm128_kernel<1><<<gemm_blocks, 256, 0, stream>>>(x, Wsp, cbp, dwp, out, N);

        // aggregate
        gather_kernel<<<(N + 3) / 4, 256, 0, stream>>>(rows_s, norms_s, offs, kbuf, qbuf, vbuf, dwp, out, N);
    }
}

// Round 3
// 788.934 us; speedup vs baseline: 5.8598x; 1.3931x over previous
//
#include <hip/hip_runtime.h>

#define CDIM 128
#define SCAN_BLK 512

typedef __attribute__((ext_vector_type(8))) short short8;
typedef __attribute__((ext_vector_type(4))) float f32x4;

__device__ __forceinline__ unsigned short f2bf(float f) {
    unsigned int u = __float_as_uint(f);
    u = (u + 0x7FFF + ((u >> 16) & 1)) >> 16;  // RNE
    return (unsigned short)u;
}
__device__ __forceinline__ float bflo(unsigned int w) { return __uint_as_float(w << 16); }
__device__ __forceinline__ float bfhi(unsigned int w) { return __uint_as_float(w & 0xFFFF0000u); }

// ---------------- softmax over P=3 of d[3][128] -> dw[3][128] ----------------
__global__ void softmax_dw_kernel(const float* __restrict__ d, float* __restrict__ dw) {
    int c = threadIdx.x;
    float d0 = d[0 * CDIM + c], d1 = d[1 * CDIM + c], d2 = d[2 * CDIM + c];
    float m = fmaxf(d0, fmaxf(d1, d2));
    float e0 = expf(d0 - m), e1 = expf(d1 - m), e2 = expf(d2 - m);
    float inv = 1.0f / (e0 + e1 + e2);
    dw[0 * CDIM + c] = e0 * inv;
    dw[1 * CDIM + c] = e1 * inv;
    dw[2 * CDIM + c] = e2 * inv;
}

// ---------------- out[n][c] = hop_bias[c] ----------------
__global__ void init_out_kernel(float* __restrict__ out, const float* __restrict__ hop_bias, int total) {
    int i = blockIdx.x * blockDim.x + threadIdx.x;
    if (i < total) out[i] = hop_bias[i & (CDIM - 1)];
}

// ---------------- x fp32 -> bf16, padded rows zeroed ----------------
__global__ void conv_x_kernel(const float* __restrict__ x, unsigned short* __restrict__ x16,
                              int total, int padded_total) {
    int i8 = (blockIdx.x * blockDim.x + threadIdx.x) * 8;
    if (i8 >= padded_total) return;
    unsigned short o[8];
    if (i8 + 8 <= total) {
        float4 a = *reinterpret_cast<const float4*>(x + i8);
        float4 b = *reinterpret_cast<const float4*>(x + i8 + 4);
        o[0] = f2bf(a.x); o[1] = f2bf(a.y); o[2] = f2bf(a.z); o[3] = f2bf(a.w);
        o[4] = f2bf(b.x); o[5] = f2bf(b.y); o[6] = f2bf(b.z); o[7] = f2bf(b.w);
    } else {
        for (int j = 0; j < 8; ++j) o[j] = 0;
    }
    *reinterpret_cast<short8*>(x16 + i8) = *reinterpret_cast<short8*>(o);
}

// ---------------- W (Wk,Wq,Wv,Wskip fp32 [3][128][128]) -> w16 [hop][proj][c][k] ----------------
__global__ void conv_w_kernel(const float* __restrict__ Wk, const float* __restrict__ Wq,
                              const float* __restrict__ Wv, const float* __restrict__ Ws,
                              unsigned short* __restrict__ w16) {
    int i = blockIdx.x * blockDim.x + threadIdx.x;  // over 3*4*16384
    int el = i & 16383;
    int pj = (i >> 14) & 3;
    int hop = i >> 16;
    if (hop >= 3) return;
    const float* src = (pj == 0) ? Wk : (pj == 1) ? Wq : (pj == 2) ? Wv : Ws;
    w16[i] = f2bf(src[(size_t)hop * 16384 + el]);
}

// ---------------- degree count, all 3 hops ----------------
__global__ void deg3_kernel(const int* __restrict__ ei0, const int* __restrict__ ei1,
                            const int* __restrict__ ei2, int* __restrict__ deg_all, int E, int N) {
    int e = blockIdx.x * blockDim.x + threadIdx.x;
    if (e >= E) return;
    int p = blockIdx.y;
    const int* ei = (p == 0) ? ei0 : (p == 1) ? ei1 : ei2;
    atomicAdd(&deg_all[p * N + ei[E + e]], 1);
}

// ---------------- scan A: per-block totals ----------------
__global__ __launch_bounds__(SCAN_BLK) void scanA_kernel(const int* __restrict__ deg, int* __restrict__ bsum, int n) {
    __shared__ int s[SCAN_BLK];
    int t = threadIdx.x;
    int idx = blockIdx.x * SCAN_BLK + t;
    s[t] = (idx < n) ? deg[idx] : 0;
    __syncthreads();
    for (int off = SCAN_BLK / 2; off > 0; off >>= 1) {
        if (t < off) s[t] += s[t + off];
        __syncthreads();
    }
    if (t == 0) bsum[blockIdx.x] = s[0];
}

// ---------------- scan B: exclusive scan of block sums ----------------
__global__ void scanB_kernel(int* __restrict__ bsum, int nb) {
    __shared__ int s[SCAN_BLK];
    int t = threadIdx.x;
    if (t < nb) s[t] = bsum[t];
    __syncthreads();
    if (t == 0) {
        int run = 0;
        for (int i = 0; i < nb; ++i) { int v = s[i]; s[i] = run; run += v; }
    }
    __syncthreads();
    if (t < nb) bsum[t] = s[t];
}

// ---------------- scan C: exclusive scan + cursor + dinv ----------------
__global__ __launch_bounds__(SCAN_BLK) void scanC_kernel(const int* __restrict__ deg, const int* __restrict__ bsum,
                                                         int* __restrict__ offs, int* __restrict__ cursor,
                                                         float* __restrict__ dinv, int n, int Etot) {
    __shared__ int s[SCAN_BLK];
    int t = threadIdx.x;
    int idx = blockIdx.x * SCAN_BLK + t;
    int v = (idx < n) ? deg[idx] : 0;
    s[t] = v;
    __syncthreads();
    for (int off = 1; off < SCAN_BLK; off <<= 1) {
        int a = (t >= off) ? s[t - off] : 0;
        __syncthreads();
        s[t] += a;
        __syncthreads();
    }
    if (idx < n) {
        int ex = s[t] - v + bsum[blockIdx.x];
        offs[idx] = ex;
        cursor[idx] = ex;
        dinv[idx] = v > 0 ? rsqrtf((float)v) : 0.0f;
    }
    if (idx == n - 1) offs[n] = Etot;
}

// ---------------- scatter edges into CSR buckets (int2 = {row, norm}) ----------------
__global__ __launch_bounds__(256) void scatter3_kernel(
    const int* __restrict__ ei0, const int* __restrict__ ei1, const int* __restrict__ ei2,
    const float* __restrict__ ew0, const float* __restrict__ ew1, const float* __restrict__ ew2,
    const float* __restrict__ dinv_all, int* __restrict__ cursor,
    int2* __restrict__ edata, int E, int N) {
    int e = blockIdx.x * blockDim.x + threadIdx.x;
    if (e >= E) return;
    int p = blockIdx.y;
    const int* ei = (p == 0) ? ei0 : (p == 1) ? ei1 : ei2;
    const float* ew = (p == 0) ? ew0 : (p == 1) ? ew1 : ew2;
    int row = ei[e];
    int col = ei[E + e];
    float nrm = dinv_all[p * N + row] * dinv_all[p * N + col] * ew[e];
    int pos = atomicAdd(&cursor[p * N + col], 1);
    edata[pos] = make_int2(row, __float_as_int(nrm));
}

// ---------------- fused bf16 MFMA GEMM: 4 projections via blockIdx.y ----------------
// y[r][c] = sum_k x[r][k] * W[c][k] + bias[c]
// proj 0 -> kbuf bf16 [r][c]; proj 1 -> qv[r][2c]; proj 2 -> qv[r][2c+1];
// proj 3 -> out[r][c] += dw[c] * (acc + cbias[c])
__global__ __launch_bounds__(256) void gemm_mfma_kernel(
    const unsigned short* __restrict__ x16, const unsigned short* __restrict__ w16,
    const float* __restrict__ bk, const float* __restrict__ bq, const float* __restrict__ bv,
    const float* __restrict__ cb, const float* __restrict__ dwp,
    unsigned short* __restrict__ kbuf, unsigned short* __restrict__ qv,
    float* __restrict__ out, int N) {
    const int proj = blockIdx.y;
    const int row0 = blockIdx.x * 128;
    const int tid = threadIdx.x;
    const int w = tid >> 6;
    const int lane = tid & 63;
    const int wr = w >> 1;   // 0..1 (row half)
    const int wc = w & 1;    // 0..1 (col half)
    const int l15 = lane & 15;
    const int lg = lane >> 4;  // 0..3

    const unsigned short* wp = w16 + (size_t)proj * 16384;

    f32x4 acc[4][4];
#pragma unroll
    for (int m = 0; m < 4; ++m)
#pragma unroll
        for (int n = 0; n < 4; ++n) acc[m][n] = (f32x4){0.f, 0.f, 0.f, 0.f};

#pragma unroll
    for (int ks = 0; ks < 4; ++ks) {
        const int k0 = ks * 32 + lg * 8;
        short8 a[4], b[4];
#pragma unroll
        for (int m = 0; m < 4; ++m) {
            int row = row0 + wr * 64 + m * 16 + l15;
            a[m] = *reinterpret_cast<const short8*>(x16 + (size_t)row * CDIM + k0);
        }
#pragma unroll
        for (int n = 0; n < 4; ++n) {
            int col = wc * 64 + n * 16 + l15;
            b[n] = *reinterpret_cast<const short8*>(wp + (size_t)col * CDIM + k0);
        }
#pragma unroll
        for (int m = 0; m < 4; ++m)
#pragma unroll
            for (int n = 0; n < 4; ++n)
                acc[m][n] = __builtin_amdgcn_mfma_f32_16x16x32_bf16(a[m], b[n], acc[m][n], 0, 0, 0);
    }

    // epilogue
    const float* bias = (proj == 0) ? bk : (proj == 1) ? bq : (proj == 2) ? bv : cb;
#pragma unroll
    for (int n = 0; n < 4; ++n) {
        int col = wc * 64 + n * 16 + l15;
        float bb = bias[col];
        float dd = (proj == 3) ? dwp[col] : 0.0f;
#pragma unroll
        for (int m = 0; m < 4; ++m) {
#pragma unroll
            for (int r = 0; r < 4; ++r) {
                int row = row0 + wr * 64 + m * 16 + lg * 4 + r;
                if (row < N) {
                    float val = acc[m][n][r] + bb;
                    if (proj == 0) {
                        kbuf[(size_t)row * CDIM + col] = f2bf(val);
                    } else if (proj == 1) {
                        qv[(size_t)row * 2 * CDIM + 2 * col] = f2bf(val);
                    } else if (proj == 2) {
                        qv[(size_t)row * 2 * CDIM + 2 * col + 1] = f2bf(val);
                    } else {
                        out[(size_t)row * CDIM + col] += dd * val;
                    }
                }
            }
        }
    }
}

// ---------------- gather: one wave per node; lane owns 2 channels ----------------
__global__ __launch_bounds__(256) void gather_kernel(
    const int2* __restrict__ edata, const int* __restrict__ offs,
    const unsigned short* __restrict__ kbuf, const unsigned short* __restrict__ qv,
    const float* __restrict__ dwp, float* __restrict__ out, int N) {
    int node = blockIdx.x * 4 + (threadIdx.x >> 6);
    if (node >= N) return;
    int lane = threadIdx.x & 63;
    int start = offs[node];
    int end = offs[node + 1];
    unsigned int kw = *reinterpret_cast<const unsigned int*>(kbuf + (size_t)node * CDIM + lane * 2);
    float k0 = bflo(kw), k1 = bfhi(kw);
    float accx = 0.f, accy = 0.f;
    for (int j = start; j < end; ++j) {
        int2 e = edata[j];  // uniform across lanes -> broadcast
        int row = e.x;
        float nrm = __int_as_float(e.y);
        uint2 qvw = *reinterpret_cast<const uint2*>(qv + (size_t)row * 2 * CDIM + lane * 4);
        float q0 = bflo(qvw.x), v0 = bfhi(qvw.x);
        float q1 = bflo(qvw.y), v1 = bfhi(qvw.y);
        float s0 = nrm / (1.0f + __expf(-(k0 + q0)));
        float s1 = nrm / (1.0f + __expf(-(k1 + q1)));
        accx = fmaf(s0, v0, accx);
        accy = fmaf(s1, v1, accy);
    }
    float2 dd = *reinterpret_cast<const float2*>(dwp + lane * 2);
    float2* op = reinterpret_cast<float2*>(out + (size_t)node * CDIM + lane * 2);
    float2 o = *op;
    o.x += accx * dd.x;
    o.y += accy * dd.y;
    *op = o;
}

extern "C" void kernel_launch(void* const* d_in, const int* in_sizes, int n_in,
                              void* d_out, int out_size, void* d_ws, size_t ws_size,
                              hipStream_t stream) {
    const float* x = (const float*)d_in[0];
    const int* ei0 = (const int*)d_in[1];
    const int* ei1 = (const int*)d_in[2];
    const int* ei2 = (const int*)d_in[3];
    const float* ew0 = (const float*)d_in[4];
    const float* ew1 = (const float*)d_in[5];
    const float* ew2 = (const float*)d_in[6];
    const float* Wk = (const float*)d_in[7];
    const float* bk = (const float*)d_in[8];
    const float* Wq = (const float*)d_in[9];
    const float* bq = (const float*)d_in[10];
    const float* Wv = (const float*)d_in[11];
    const float* bv = (const float*)d_in[12];
    const float* Wskip = (const float*)d_in[13];
    const float* cbias = (const float*)d_in[14];
    const float* d = (const float*)d_in[15];
    const float* hop_bias = (const float*)d_in[16];
    float* out = (float*)d_out;

    const int N = in_sizes[0] / CDIM;  // 50000
    const int E = in_sizes[4];         // 800000
    const int Npad = (N + 127) & ~127; // 50048
    const int n3 = 3 * N;
    const int nb = (n3 + SCAN_BLK - 1) / SCAN_BLK;

    // workspace layout (16B-aligned carve-outs)
    char* wsp = (char*)d_ws;
    float* dw = (float*)wsp;                  wsp += 3 * CDIM * sizeof(float);
    unsigned short* x16 = (unsigned short*)wsp;  wsp += (size_t)Npad * CDIM * sizeof(unsigned short);
    unsigned short* w16 = (unsigned short*)wsp;  wsp += (size_t)3 * 4 * 16384 * sizeof(unsigned short);
    unsigned short* kbuf = (unsigned short*)wsp; wsp += (size_t)N * CDIM * sizeof(unsigned short);
    unsigned short* qv = (unsigned short*)wsp;   wsp += (size_t)N * 2 * CDIM * sizeof(unsigned short);
    int* deg_all = (int*)wsp;                 wsp += (size_t)n3 * sizeof(int);
    float* dinv_all = (float*)wsp;            wsp += (size_t)n3 * sizeof(float);
    int* offs_all = (int*)wsp;                wsp += (size_t)(n3 + 4) * sizeof(int);
    int* cursor = (int*)wsp;                  wsp += (size_t)n3 * sizeof(int);
    int* bsum = (int*)wsp;                    wsp += SCAN_BLK * sizeof(int);
    int2* edata = (int2*)wsp;                 wsp += (size_t)3 * E * sizeof(int2);

    softmax_dw_kernel<<<1, CDIM, 0, stream>>>(d, dw);
    init_out_kernel<<<(N * CDIM + 255) / 256, 256, 0, stream>>>(out, hop_bias, N * CDIM);
    conv_x_kernel<<<(Npad * CDIM / 8 + 255) / 256, 256, 0, stream>>>(x, x16, N * CDIM, Npad * CDIM);
    conv_w_kernel<<<(3 * 4 * 16384 + 255) / 256, 256, 0, stream>>>(Wk, Wq, Wv, Wskip, w16);

    hipMemsetAsync(deg_all, 0, (size_t)n3 * sizeof(int), stream);
    deg3_kernel<<<dim3((E + 511) / 512, 3), 512, 0, stream>>>(ei0, ei1, ei2, deg_all, E, N);
    scanA_kernel<<<nb, SCAN_BLK, 0, stream>>>(deg_all, bsum, n3);
    scanB_kernel<<<1, SCAN_BLK, 0, stream>>>(bsum, nb);
    scanC_kernel<<<nb, SCAN_BLK, 0, stream>>>(deg_all, bsum, offs_all, cursor, dinv_all, n3, 3 * E);
    scatter3_kernel<<<dim3((E + 255) / 256, 3), 256, 0, stream>>>(
        ei0, ei1, ei2, ew0, ew1, ew2, dinv_all, cursor, edata, E, N);

    const int gemm_blocks = (N + 127) / 128;
    for (int p = 0; p < 3; ++p) {
        gemm_mfma_kernel<<<dim3(gemm_blocks, 4), 256, 0, stream>>>(
            x16, w16 + (size_t)p * 4 * 16384,
            bk + (size_t)p * CDIM, bq + (size_t)p * CDIM, bv + (size_t)p * CDIM,
            cbias + (size_t)p * CDIM, dw + (size_t)p * CDIM,
            kbuf, qv, out, N);
        gather_kernel<<<(N + 3) / 4, 256, 0, stream>>>(
            edata, offs_all + (size_t)p * N, kbuf, qv, dw + (size_t)p * CDIM, out, N);
    }
}

// Round 4
// 575.434 us; speedup vs baseline: 8.0340x; 1.3710x over previous
//
#include <hip/hip_runtime.h>

#define CDIM 128
#define SCAN_BLK 512

typedef __attribute__((ext_vector_type(8))) short short8;
typedef __attribute__((ext_vector_type(4))) float f32x4;

__device__ __forceinline__ unsigned short f2bf(float f) {
    unsigned int u = __float_as_uint(f);
    u = (u + 0x7FFF + ((u >> 16) & 1)) >> 16;  // RNE
    return (unsigned short)u;
}
__device__ __forceinline__ float bflo(unsigned int w) { return __uint_as_float(w << 16); }
__device__ __forceinline__ float bfhi(unsigned int w) { return __uint_as_float(w & 0xFFFF0000u); }

// ---------------- softmax over P=3 of d[3][128] -> dw[3][128] ----------------
__global__ void softmax_dw_kernel(const float* __restrict__ d, float* __restrict__ dw) {
    int c = threadIdx.x;
    float d0 = d[0 * CDIM + c], d1 = d[1 * CDIM + c], d2 = d[2 * CDIM + c];
    float m = fmaxf(d0, fmaxf(d1, d2));
    float e0 = expf(d0 - m), e1 = expf(d1 - m), e2 = expf(d2 - m);
    float inv = 1.0f / (e0 + e1 + e2);
    dw[0 * CDIM + c] = e0 * inv;
    dw[1 * CDIM + c] = e1 * inv;
    dw[2 * CDIM + c] = e2 * inv;
}

// ---------------- x fp32 -> bf16, padded rows zeroed ----------------
__global__ void conv_x_kernel(const float* __restrict__ x, unsigned short* __restrict__ x16,
                              int total, int padded_total) {
    int i8 = (blockIdx.x * blockDim.x + threadIdx.x) * 8;
    if (i8 >= padded_total) return;
    unsigned short o[8];
    if (i8 + 8 <= total) {
        float4 a = *reinterpret_cast<const float4*>(x + i8);
        float4 b = *reinterpret_cast<const float4*>(x + i8 + 4);
        o[0] = f2bf(a.x); o[1] = f2bf(a.y); o[2] = f2bf(a.z); o[3] = f2bf(a.w);
        o[4] = f2bf(b.x); o[5] = f2bf(b.y); o[6] = f2bf(b.z); o[7] = f2bf(b.w);
    } else {
        for (int j = 0; j < 8; ++j) o[j] = 0;
    }
    *reinterpret_cast<short8*>(x16 + i8) = *reinterpret_cast<short8*>(o);
}

// ---------------- Wk,Wq,Wv fp32 [3][128][128] -> w16 [hop][proj3][c][k] bf16 ----------------
__global__ void conv_w_kernel(const float* __restrict__ Wk, const float* __restrict__ Wq,
                              const float* __restrict__ Wv, unsigned short* __restrict__ w16) {
    int i = blockIdx.x * blockDim.x + threadIdx.x;  // over 3*3*16384
    if (i >= 3 * 3 * 16384) return;
    int hop = i / 49152;
    int r = i - hop * 49152;
    int pj = r >> 14;
    int el = r & 16383;
    const float* src = (pj == 0) ? Wk : (pj == 1) ? Wq : Wv;
    w16[i] = f2bf(src[(size_t)hop * 16384 + el]);
}

// ---------------- skip fusion: W'[c,k]=sum_p dw[p][c]*Wskip[p][c][k]; b'[c] ----------------
__global__ void prep_skip_kernel(const float* __restrict__ Wskip, const float* __restrict__ cbias,
                                 const float* __restrict__ hop_bias, const float* __restrict__ dw,
                                 unsigned short* __restrict__ wskip16, float* __restrict__ biasS) {
    int i = blockIdx.x * blockDim.x + threadIdx.x;
    if (i >= 16384) return;
    int c = i >> 7;
    float acc = dw[0 * CDIM + c] * Wskip[0 * 16384 + i] +
                dw[1 * CDIM + c] * Wskip[1 * 16384 + i] +
                dw[2 * CDIM + c] * Wskip[2 * 16384 + i];
    wskip16[i] = f2bf(acc);
    if ((i & 127) == 0) {
        float b = dw[0 * CDIM + c] * cbias[0 * CDIM + c] +
                  dw[1 * CDIM + c] * cbias[1 * CDIM + c] +
                  dw[2 * CDIM + c] * cbias[2 * CDIM + c];
        biasS[c] = b + hop_bias[c];
    }
}

// ---------------- degree count, all 3 hops ----------------
__global__ void deg3_kernel(const int* __restrict__ ei0, const int* __restrict__ ei1,
                            const int* __restrict__ ei2, int* __restrict__ deg_all, int E, int N) {
    int e = blockIdx.x * blockDim.x + threadIdx.x;
    if (e >= E) return;
    int p = blockIdx.y;
    const int* ei = (p == 0) ? ei0 : (p == 1) ? ei1 : ei2;
    atomicAdd(&deg_all[p * N + ei[E + e]], 1);
}

// ---------------- scan A: per-block totals ----------------
__global__ __launch_bounds__(SCAN_BLK) void scanA_kernel(const int* __restrict__ deg, int* __restrict__ bsum, int n) {
    __shared__ int s[SCAN_BLK];
    int t = threadIdx.x;
    int idx = blockIdx.x * SCAN_BLK + t;
    s[t] = (idx < n) ? deg[idx] : 0;
    __syncthreads();
    for (int off = SCAN_BLK / 2; off > 0; off >>= 1) {
        if (t < off) s[t] += s[t + off];
        __syncthreads();
    }
    if (t == 0) bsum[blockIdx.x] = s[0];
}

// ---------------- scan B: exclusive scan of block sums ----------------
__global__ void scanB_kernel(int* __restrict__ bsum, int nb) {
    __shared__ int s[SCAN_BLK];
    int t = threadIdx.x;
    if (t < nb) s[t] = bsum[t];
    __syncthreads();
    if (t == 0) {
        int run = 0;
        for (int i = 0; i < nb; ++i) { int v = s[i]; s[i] = run; run += v; }
    }
    __syncthreads();
    if (t < nb) bsum[t] = s[t];
}

// ---------------- scan C: exclusive scan + cursor + dinv ----------------
__global__ __launch_bounds__(SCAN_BLK) void scanC_kernel(const int* __restrict__ deg, const int* __restrict__ bsum,
                                                         int* __restrict__ offs, int* __restrict__ cursor,
                                                         float* __restrict__ dinv, int n, int Etot) {
    __shared__ int s[SCAN_BLK];
    int t = threadIdx.x;
    int idx = blockIdx.x * SCAN_BLK + t;
    int v = (idx < n) ? deg[idx] : 0;
    s[t] = v;
    __syncthreads();
    for (int off = 1; off < SCAN_BLK; off <<= 1) {
        int a = (t >= off) ? s[t - off] : 0;
        __syncthreads();
        s[t] += a;
        __syncthreads();
    }
    if (idx < n) {
        int ex = s[t] - v + bsum[blockIdx.x];
        offs[idx] = ex;
        cursor[idx] = ex;
        dinv[idx] = v > 0 ? rsqrtf((float)v) : 0.0f;
    }
    if (idx == n - 1) offs[n] = Etot;
}

// ---------------- scatter edges into CSR buckets (int2 = {row, norm}) ----------------
__global__ __launch_bounds__(256) void scatter3_kernel(
    const int* __restrict__ ei0, const int* __restrict__ ei1, const int* __restrict__ ei2,
    const float* __restrict__ ew0, const float* __restrict__ ew1, const float* __restrict__ ew2,
    const float* __restrict__ dinv_all, int* __restrict__ cursor,
    int2* __restrict__ edata, int E, int N) {
    int e = blockIdx.x * blockDim.x + threadIdx.x;
    if (e >= E) return;
    int p = blockIdx.y;
    const int* ei = (p == 0) ? ei0 : (p == 1) ? ei1 : ei2;
    const float* ew = (p == 0) ? ew0 : (p == 1) ? ew1 : ew2;
    int row = ei[e];
    int col = ei[E + e];
    float nrm = dinv_all[p * N + row] * dinv_all[p * N + col] * ew[e];
    int pos = atomicAdd(&cursor[p * N + col], 1);
    edata[pos] = make_int2(row, __float_as_int(nrm));
}

// ---------------- bf16 MFMA GEMM ----------------
// SKIP=0: proj=blockIdx.y -> 0:kbuf, 1:qv even, 2:qv odd
// SKIP=1: out[r][c] = acc + biasS[c] (store)
template <int SKIP>
__global__ __launch_bounds__(256) void gemm_mfma_kernel(
    const unsigned short* __restrict__ x16, const unsigned short* __restrict__ wbase,
    const float* __restrict__ b0, const float* __restrict__ b1, const float* __restrict__ b2,
    unsigned short* __restrict__ kbuf, unsigned short* __restrict__ qv,
    float* __restrict__ out, int N) {
    const int proj = SKIP ? 3 : blockIdx.y;
    const int row0 = blockIdx.x * 128;
    const int tid = threadIdx.x;
    const int w = tid >> 6;
    const int lane = tid & 63;
    const int wr = w >> 1;
    const int wc = w & 1;
    const int l15 = lane & 15;
    const int lg = lane >> 4;

    const unsigned short* wp = SKIP ? wbase : wbase + (size_t)proj * 16384;

    f32x4 acc[4][4];
#pragma unroll
    for (int m = 0; m < 4; ++m)
#pragma unroll
        for (int n = 0; n < 4; ++n) acc[m][n] = (f32x4){0.f, 0.f, 0.f, 0.f};

#pragma unroll
    for (int ks = 0; ks < 4; ++ks) {
        const int k0 = ks * 32 + lg * 8;
        short8 a[4], b[4];
#pragma unroll
        for (int m = 0; m < 4; ++m) {
            int row = row0 + wr * 64 + m * 16 + l15;
            a[m] = *reinterpret_cast<const short8*>(x16 + (size_t)row * CDIM + k0);
        }
#pragma unroll
        for (int n = 0; n < 4; ++n) {
            int col = wc * 64 + n * 16 + l15;
            b[n] = *reinterpret_cast<const short8*>(wp + (size_t)col * CDIM + k0);
        }
#pragma unroll
        for (int m = 0; m < 4; ++m)
#pragma unroll
            for (int n = 0; n < 4; ++n)
                acc[m][n] = __builtin_amdgcn_mfma_f32_16x16x32_bf16(a[m], b[n], acc[m][n], 0, 0, 0);
    }

    const float* bias = SKIP ? b0 : (proj == 0) ? b0 : (proj == 1) ? b1 : b2;
#pragma unroll
    for (int n = 0; n < 4; ++n) {
        int col = wc * 64 + n * 16 + l15;
        float bb = bias[col];
#pragma unroll
        for (int m = 0; m < 4; ++m) {
#pragma unroll
            for (int r = 0; r < 4; ++r) {
                int row = row0 + wr * 64 + m * 16 + lg * 4 + r;
                if (row < N) {
                    float val = acc[m][n][r] + bb;
                    if (SKIP) {
                        out[(size_t)row * CDIM + col] = val;
                    } else if (proj == 0) {
                        kbuf[(size_t)row * CDIM + col] = f2bf(val);
                    } else if (proj == 1) {
                        qv[(size_t)row * 2 * CDIM + 2 * col] = f2bf(val);
                    } else {
                        qv[(size_t)row * 2 * CDIM + 2 * col + 1] = f2bf(val);
                    }
                }
            }
        }
    }
}

// ---------------- gather: one wave per node, 4-deep ILP on qv loads ----------------
__device__ __forceinline__ void edge_acc(unsigned int wx, unsigned int wy, float nrm,
                                         float k0, float k1, float& ax, float& ay) {
    float q0 = bflo(wx), v0 = bfhi(wx);
    float q1 = bflo(wy), v1 = bfhi(wy);
    ax = fmaf(nrm / (1.0f + __expf(-(k0 + q0))), v0, ax);
    ay = fmaf(nrm / (1.0f + __expf(-(k1 + q1))), v1, ay);
}

__global__ __launch_bounds__(256) void gather_kernel(
    const int2* __restrict__ edata, const int* __restrict__ offs,
    const unsigned short* __restrict__ kbuf, const unsigned short* __restrict__ qv,
    const float* __restrict__ dwp, float* __restrict__ out, int N) {
    int node = blockIdx.x * 4 + (threadIdx.x >> 6);
    if (node >= N) return;
    int lane = threadIdx.x & 63;
    int start = offs[node];
    int end = offs[node + 1];
    unsigned int kw = *reinterpret_cast<const unsigned int*>(kbuf + (size_t)node * CDIM + lane * 2);
    float k0 = bflo(kw), k1 = bfhi(kw);
    float ax = 0.f, ay = 0.f;

    for (int chunk = start; chunk < end; chunk += 64) {
        int cnt = min(64, end - chunk);
        int2 meta = make_int2(0, 0);
        if (chunk + lane < end) meta = edata[chunk + lane];
        int j = 0;
        for (; j + 4 <= cnt; j += 4) {
            int r0 = __shfl(meta.x, j + 0);
            int r1 = __shfl(meta.x, j + 1);
            int r2 = __shfl(meta.x, j + 2);
            int r3 = __shfl(meta.x, j + 3);
            uint2 w0 = *reinterpret_cast<const uint2*>(qv + (size_t)r0 * 2 * CDIM + lane * 4);
            uint2 w1 = *reinterpret_cast<const uint2*>(qv + (size_t)r1 * 2 * CDIM + lane * 4);
            uint2 w2 = *reinterpret_cast<const uint2*>(qv + (size_t)r2 * 2 * CDIM + lane * 4);
            uint2 w3 = *reinterpret_cast<const uint2*>(qv + (size_t)r3 * 2 * CDIM + lane * 4);
            float n0 = __int_as_float(__shfl(meta.y, j + 0));
            float n1 = __int_as_float(__shfl(meta.y, j + 1));
            float n2 = __int_as_float(__shfl(meta.y, j + 2));
            float n3 = __int_as_float(__shfl(meta.y, j + 3));
            edge_acc(w0.x, w0.y, n0, k0, k1, ax, ay);
            edge_acc(w1.x, w1.y, n1, k0, k1, ax, ay);
            edge_acc(w2.x, w2.y, n2, k0, k1, ax, ay);
            edge_acc(w3.x, w3.y, n3, k0, k1, ax, ay);
        }
        for (; j < cnt; ++j) {
            int r = __shfl(meta.x, j);
            float nn = __int_as_float(__shfl(meta.y, j));
            uint2 ww = *reinterpret_cast<const uint2*>(qv + (size_t)r * 2 * CDIM + lane * 4);
            edge_acc(ww.x, ww.y, nn, k0, k1, ax, ay);
        }
    }

    float2 dd = *reinterpret_cast<const float2*>(dwp + lane * 2);
    float2* op = reinterpret_cast<float2*>(out + (size_t)node * CDIM + lane * 2);
    float2 o = *op;
    o.x += ax * dd.x;
    o.y += ay * dd.y;
    *op = o;
}

extern "C" void kernel_launch(void* const* d_in, const int* in_sizes, int n_in,
                              void* d_out, int out_size, void* d_ws, size_t ws_size,
                              hipStream_t stream) {
    const float* x = (const float*)d_in[0];
    const int* ei0 = (const int*)d_in[1];
    const int* ei1 = (const int*)d_in[2];
    const int* ei2 = (const int*)d_in[3];
    const float* ew0 = (const float*)d_in[4];
    const float* ew1 = (const float*)d_in[5];
    const float* ew2 = (const float*)d_in[6];
    const float* Wk = (const float*)d_in[7];
    const float* bk = (const float*)d_in[8];
    const float* Wq = (const float*)d_in[9];
    const float* bq = (const float*)d_in[10];
    const float* Wv = (const float*)d_in[11];
    const float* bv = (const float*)d_in[12];
    const float* Wskip = (const float*)d_in[13];
    const float* cbias = (const float*)d_in[14];
    const float* d = (const float*)d_in[15];
    const float* hop_bias = (const float*)d_in[16];
    float* out = (float*)d_out;

    const int N = in_sizes[0] / CDIM;  // 50000
    const int E = in_sizes[4];         // 800000
    const int Npad = (N + 127) & ~127;
    const int n3 = 3 * N;
    const int nb = (n3 + SCAN_BLK - 1) / SCAN_BLK;

    // workspace layout (all carve-outs 16B-multiples)
    char* wsp = (char*)d_ws;
    float* dw = (float*)wsp;                     wsp += 3 * CDIM * sizeof(float);
    float* biasS = (float*)wsp;                  wsp += CDIM * sizeof(float);
    unsigned short* x16 = (unsigned short*)wsp;  wsp += (size_t)Npad * CDIM * sizeof(unsigned short);
    unsigned short* w16 = (unsigned short*)wsp;  wsp += (size_t)3 * 3 * 16384 * sizeof(unsigned short);
    unsigned short* wskip16 = (unsigned short*)wsp; wsp += (size_t)16384 * sizeof(unsigned short);
    unsigned short* kbuf = (unsigned short*)wsp; wsp += (size_t)N * CDIM * sizeof(unsigned short);
    unsigned short* qv = (unsigned short*)wsp;   wsp += (size_t)N * 2 * CDIM * sizeof(unsigned short);
    int* deg_all = (int*)wsp;                    wsp += (size_t)n3 * sizeof(int);
    float* dinv_all = (float*)wsp;               wsp += (size_t)n3 * sizeof(float);
    int* offs_all = (int*)wsp;                   wsp += (size_t)(n3 + 4) * sizeof(int);
    int* cursor = (int*)wsp;                     wsp += (size_t)n3 * sizeof(int);
    int* bsum = (int*)wsp;                       wsp += SCAN_BLK * sizeof(int);
    int2* edata = (int2*)wsp;                    wsp += (size_t)3 * E * sizeof(int2);

    softmax_dw_kernel<<<1, CDIM, 0, stream>>>(d, dw);
    conv_x_kernel<<<(Npad * CDIM / 8 + 255) / 256, 256, 0, stream>>>(x, x16, N * CDIM, Npad * CDIM);
    conv_w_kernel<<<(3 * 3 * 16384 + 255) / 256, 256, 0, stream>>>(Wk, Wq, Wv, w16);
    prep_skip_kernel<<<(16384 + 255) / 256, 256, 0, stream>>>(Wskip, cbias, hop_bias, dw, wskip16, biasS);

    hipMemsetAsync(deg_all, 0, (size_t)n3 * sizeof(int), stream);
    deg3_kernel<<<dim3((E + 511) / 512, 3), 512, 0, stream>>>(ei0, ei1, ei2, deg_all, E, N);
    scanA_kernel<<<nb, SCAN_BLK, 0, stream>>>(deg_all, bsum, n3);
    scanB_kernel<<<1, SCAN_BLK, 0, stream>>>(bsum, nb);
    scanC_kernel<<<nb, SCAN_BLK, 0, stream>>>(deg_all, bsum, offs_all, cursor, dinv_all, n3, 3 * E);
    scatter3_kernel<<<dim3((E + 255) / 256, 3), 256, 0, stream>>>(
        ei0, ei1, ei2, ew0, ew1, ew2, dinv_all, cursor, edata, E, N);

    const int gemm_blocks = (Npad + 127) / 128;
    // fused skip GEMM: writes out (incl. hop_bias and dw-weighted cbias)
    gemm_mfma_kernel<1><<<dim3(gemm_blocks, 1), 256, 0, stream>>>(
        x16, wskip16, biasS, nullptr, nullptr, nullptr, nullptr, out, N);

    for (int p = 0; p < 3; ++p) {
        gemm_mfma_kernel<0><<<dim3(gemm_blocks, 3), 256, 0, stream>>>(
            x16, w16 + (size_t)p * 3 * 16384,
            bk + (size_t)p * CDIM, bq + (size_t)p * CDIM, bv + (size_t)p * CDIM,
            kbuf, qv, nullptr, N);
        gather_kernel<<<(N + 3) / 4, 256, 0, stream>>>(
            edata, offs_all + (size_t)p * N, kbuf, qv, dw + (size_t)p * CDIM, out, N);
    }
}